// Round 5
// baseline (61217.334 us; speedup 1.0000x reference)
//
#include <hip/hip_runtime.h>
#include <hip/hip_bf16.h>

typedef __attribute__((ext_vector_type(8))) short short8;
typedef __attribute__((ext_vector_type(4))) float f32x4;

namespace {
constexpr int kB = 256, kT = 512, kE = 512, kH = 1024;
constexpr int CH = 48;     // K chunks of 32 (0-31: h/Whh region, 32-47: emb/Wih region)
constexpr int NT = 256;
constexpr int VOCAB = 32000;

// ws layout (bytes). W pack: [jg 32][chunk 48][pl*4+kg 12][col 96][8] bf16
// X pack:  [buf 2][chunk 48][pl*4+kg 12][row 256][8] bf16
constexpr size_t W_ELEMS = (size_t)32 * CH * 12 * 96 * 8;
constexpr size_t X_ELEMS_BUF = (size_t)CH * 12 * 256 * 8;
constexpr size_t OFF_W = 0;
constexpr size_t OFF_X = W_ELEMS * 2;                       // 28,311,552
constexpr size_t OFF_H = OFF_X + X_ELEMS_BUF * 2 * 2;       // 33,030,144
constexpr size_t OFF_BIAS = OFF_H + (size_t)2 * kB * kH * 4; // 35,127,296
constexpr size_t WS_NEED = OFF_BIAS + (size_t)32 * 2 * 96 * 4;
}

__device__ __forceinline__ unsigned short f2bf(float f) {
    __hip_bfloat16 h = __float2bfloat16(f);
    return *reinterpret_cast<unsigned short*>(&h);
}
__device__ __forceinline__ float bf2f(unsigned short u) {
    __hip_bfloat16 h = *reinterpret_cast<__hip_bfloat16*>(&u);
    return __bfloat162float(h);
}

#define MFMA16(A_, B_, C_) __builtin_amdgcn_mfma_f32_16x16x32_bf16((A_), (B_), (C_), 0, 0, 0)

// ---------------- prep: split+reorder weights into MFMA-ready 3-plane pack ----
// col packing within a block's 96 cols: [16 r][16 z][16 n] x 2 groups
// (group g covers hidden u = g*16 + (col&15); j = jg*32 + u; W row = type*1024 + j)
__global__ void __launch_bounds__(256)
prep_w(const float* __restrict__ Wih, const float* __restrict__ Whh,
       const float* __restrict__ bih, const float* __restrict__ bhh,
       unsigned short* __restrict__ wsW, float* __restrict__ wsBias)
{
    const int blk = blockIdx.x;          // jg*48 + c
    const int jg = blk / CH, c = blk % CH;
    const int tid = threadIdx.x;

    for (int u0 = tid; u0 < 384; u0 += 256) {     // (col, kg) units
        int col = u0 >> 2, kg = u0 & 3;
        int type = (col % 48) >> 4;
        int uu = (col / 48) * 16 + (col & 15);
        int grow = type * kH + jg * 32 + uu;
        float v[8];
        if (c < 32) {
            int kb = c * 32 + kg * 8;
            const float4* p = (const float4*)&Whh[(size_t)grow * kH + kb];
            float4 x0 = p[0], x1 = p[1];
            v[0]=x0.x; v[1]=x0.y; v[2]=x0.z; v[3]=x0.w;
            v[4]=x1.x; v[5]=x1.y; v[6]=x1.z; v[7]=x1.w;
        } else {
            int kb = (c - 32) * 32 + kg * 8;
            const float4* p = (const float4*)&Wih[(size_t)grow * kE + kb];
            float4 x0 = p[0], x1 = p[1];
            v[0]=x0.x; v[1]=x0.y; v[2]=x0.z; v[3]=x0.w;
            v[4]=x1.x; v[5]=x1.y; v[6]=x1.z; v[7]=x1.w;
        }
        size_t base = ((size_t)blk * 12 + kg) * 768 + (size_t)col * 8;  // pl=0 slot
        #pragma unroll
        for (int e = 0; e < 8; ++e) {
            float xx = v[e];
            unsigned short q0 = f2bf(xx);
            float r1 = xx - bf2f(q0);
            unsigned short q1 = f2bf(r1);
            unsigned short q2 = f2bf(r1 - bf2f(q1));
            wsW[base + e]            = q0;
            wsW[base + 4 * 768 + e]  = q1;   // pl stride = 4 slots of 768
            wsW[base + 8 * 768 + e]  = q2;
        }
    }
    if (c == 0 && tid < 96) {
        int col = tid;
        int type = (col % 48) >> 4;
        int uu = (col / 48) * 16 + (col & 15);
        int grow = type * kH + jg * 32 + uu;
        wsBias[(jg * 2 + 0) * 96 + col] = bih[grow];
        wsBias[(jg * 2 + 1) * 96 + col] = bhh[grow];
    }
}

// ---------------- prep: build X buffer 0 (h0 planes + emb(x[:,0]) planes) -----
__global__ void __launch_bounds__(256)
prep_x0(const int* __restrict__ x, const float* __restrict__ h0,
        const float* __restrict__ emb, unsigned short* __restrict__ wsX,
        float* __restrict__ wsH)
{
    const int c = blockIdx.x;           // 0..47
    const int tid = threadIdx.x;
    #pragma unroll 2
    for (int l = 0; l < 12; ++l) {
        int unit = l * 256 + tid;       // 0..3071
        int plkg = unit >> 8, b = unit & 255;
        int pl = plkg >> 2, kg = plkg & 3;
        float v[8];
        if (c < 32) {
            int j = c * 32 + kg * 8;
            const float4* p = (const float4*)&h0[(size_t)b * kH + j];
            float4 x0 = p[0], x1 = p[1];
            v[0]=x0.x; v[1]=x0.y; v[2]=x0.z; v[3]=x0.w;
            v[4]=x1.x; v[5]=x1.y; v[6]=x1.z; v[7]=x1.w;
            if (pl == 0) {
                #pragma unroll
                for (int e = 0; e < 8; ++e) wsH[(size_t)b * kH + j + e] = v[e];
            }
        } else {
            int tok = x[(size_t)b * kT];
            tok = (tok >= 0 && tok < VOCAB) ? tok : 0;
            int ke = (c - 32) * 32 + kg * 8;
            const float4* p = (const float4*)&emb[(size_t)tok * kE + ke];
            float4 x0 = p[0], x1 = p[1];
            v[0]=x0.x; v[1]=x0.y; v[2]=x0.z; v[3]=x0.w;
            v[4]=x1.x; v[5]=x1.y; v[6]=x1.z; v[7]=x1.w;
        }
        size_t base = ((size_t)c * 12 + plkg) * 2048 + (size_t)b * 8;
        #pragma unroll
        for (int e = 0; e < 8; ++e) {
            float xx = v[e];
            unsigned short q0 = f2bf(xx);
            float r1 = xx - bf2f(q0);
            unsigned short q1 = f2bf(r1);
            unsigned short q2 = f2bf(r1 - bf2f(q1));
            unsigned short q = (pl == 0) ? q0 : ((pl == 1) ? q1 : q2);
            wsX[base + e] = q;
        }
    }
}

// ---------------- per-step MFMA GRU kernel -----------------------------------
// Grid 256 = 8 bg x 32 jg (jg%8 = XCD: W slice stays L2-resident per XCD).
// 4 waves: pair (w>>1) handles chunks of parity (w>>1); half (w&1) = 48 cols.
// Per wave tile 32x48: per chunk 15 ds_read_b128 feed 36 MFMAs (balanced).
// n-gate uses dual accumulators (anh: chunks<32 = Whh_n; ani: >=32 = Wih_n).
__global__ void __launch_bounds__(NT, 1)
gru_step_mfma(const int* __restrict__ x, const int* __restrict__ seq_len,
              const float* __restrict__ emb, const float* __restrict__ Wlin,
              const float* __restrict__ blin,
              const unsigned short* __restrict__ wsW,
              const float* __restrict__ wsBias,
              unsigned short* __restrict__ wsX, float* __restrict__ wsH,
              float* __restrict__ out, int t)
{
    __shared__ __align__(16) short lds[49152];  // 96 KB: A 4 slots x 384 int4, B 4 x 1152 int4
    __shared__ float red[NT];
    __shared__ int ssl[32];

    const int tid = threadIdx.x;
    const int bg = blockIdx.x >> 5, jg = blockIdx.x & 31;
    const int b0 = bg * 32;
    const int w = tid >> 6, lane = tid & 63, lid = lane & 15, kg = lane >> 4;

    const int bufR = t & 1, bufW = bufR ^ 1;
    const unsigned short* Xr = wsX + (size_t)bufR * X_ELEMS_BUF;
    unsigned short* Xw = wsX + (size_t)bufW * X_ELEMS_BUF;
    const float* Hr = wsH + (size_t)bufR * kB * kH;
    float* Hw = wsH + (size_t)bufW * kB * kH;

    if (tid < 32) ssl[tid] = seq_len[b0 + tid];
    __syncthreads();

    // output tap: sample b finished at step t-1 iff ssl==t (Hr holds h_t)
    if (jg == 0 && t > 0) {
        for (int b = 0; b < 32; ++b) {
            if (ssl[b] == t) {
                const float* hr = Hr + (size_t)(b0 + b) * kH;
                float p = 0.f;
                for (int k = tid; k < kH; k += NT) p += hr[k] * Wlin[k];
                red[tid] = p;
                __syncthreads();
                for (int s = NT / 2; s > 0; s >>= 1) {
                    if (tid < s) red[tid] += red[tid + s];
                    __syncthreads();
                }
                if (tid == 0) out[b0 + b] = 1.f / (1.f + expf(-(red[0] + blin[0])));
                __syncthreads();
            }
        }
    }

    const int4* gW = (const int4*)wsW;
    const int4* gX = (const int4*)Xr;
    int4* lA = (int4*)lds;                 // 4 slots x 384 units
    int4* lB = (int4*)(lds + 12288);       // 4 slots x 1152 units
    int4 pf[12];

    auto issue = [&](int pair) {           // load chunks 2*pair, 2*pair+1 -> regs
        #pragma unroll
        for (int l = 0; l < 12; ++l) {
            int u = l * 256 + tid;
            int hi = (u >= 1536);
            int cc = 2 * pair + hi;
            int v = u - (hi ? 1536 : 0);
            if (v < 1152) {
                pf[l] = gW[(size_t)(jg * CH + cc) * 1152 + v];
            } else {
                int wv = v - 1152;         // plkg = wv>>5, row = wv&31
                pf[l] = gX[(size_t)(cc * 12 + (wv >> 5)) * 256 + (b0 + (wv & 31))];
            }
        }
    };
    auto commit = [&](int pair) {          // regs -> LDS slots (c&3)
        #pragma unroll
        for (int l = 0; l < 12; ++l) {
            int u = l * 256 + tid;
            int hi = (u >= 1536);
            int cc = 2 * pair + hi;
            int v = u - (hi ? 1536 : 0);
            if (v < 1152) lB[(cc & 3) * 1152 + v] = pf[l];
            else          lA[(cc & 3) * 384 + (v - 1152)] = pf[l];
        }
    };

    f32x4 zz4 = {0.f, 0.f, 0.f, 0.f};
    f32x4 ar[2] = {zz4, zz4}, az[2] = {zz4, zz4};
    f32x4 anh[2] = {zz4, zz4}, ani[2] = {zz4, zz4};
    const int pr = w >> 1, half = w & 1;

    auto compute = [&](int c) {
        const short* A = lds + (c & 3) * 3072;
        const short* B = lds + 12288 + (c & 3) * 9216;
        short8 fa[3][2], fb[3][3];
        #pragma unroll
        for (int pl = 0; pl < 3; ++pl) {
            #pragma unroll
            for (int rg = 0; rg < 2; ++rg)
                fa[pl][rg] = *(const short8*)&A[(pl * 4 + kg) * 256 + (rg * 16 + lid) * 8];
            #pragma unroll
            for (int cg = 0; cg < 3; ++cg)
                fb[pl][cg] = *(const short8*)&B[(pl * 4 + kg) * 768 + (half * 48 + cg * 16 + lid) * 8];
        }
        const int TA[6] = {0, 0, 1, 0, 2, 1};
        const int TB[6] = {0, 1, 0, 2, 0, 1};
        #pragma unroll
        for (int s = 0; s < 6; ++s) {
            #pragma unroll
            for (int rg = 0; rg < 2; ++rg) {
                ar[rg] = MFMA16(fa[TA[s]][rg], fb[TB[s]][0], ar[rg]);
                az[rg] = MFMA16(fa[TA[s]][rg], fb[TB[s]][1], az[rg]);
            }
        }
        if (c < 32) {
            #pragma unroll
            for (int s = 0; s < 6; ++s)
                #pragma unroll
                for (int rg = 0; rg < 2; ++rg)
                    anh[rg] = MFMA16(fa[TA[s]][rg], fb[TB[s]][2], anh[rg]);
        } else {
            #pragma unroll
            for (int s = 0; s < 6; ++s)
                #pragma unroll
                for (int rg = 0; rg < 2; ++rg)
                    ani[rg] = MFMA16(fa[TA[s]][rg], fb[TB[s]][2], ani[rg]);
        }
    };

    // software pipeline: compute pair i while next pair's loads are in flight
    issue(0);
    commit(0);
    __syncthreads();
    issue(1);
    for (int i = 0; i < 24; ++i) {
        compute(2 * i + pr);
        if (i + 1 < 24) {
            commit(i + 1);                  // slots disjoint from current reads
            if (i + 2 < 24) issue(i + 2);
            __syncthreads();
        }
    }
    __syncthreads();

    // cross-pair reduction: waves 2,3 export partial accs via LDS
    float* xch = (float*)lds;
    if (w >= 2) {
        int base = ((w - 2) * 64 + lane) * 32;
        #pragma unroll
        for (int q = 0; q < 4; ++q) {
            xch[base + 0 + q]  = ar[0][q];  xch[base + 4 + q]  = ar[1][q];
            xch[base + 8 + q]  = az[0][q];  xch[base + 12 + q] = az[1][q];
            xch[base + 16 + q] = anh[0][q]; xch[base + 20 + q] = anh[1][q];
            xch[base + 24 + q] = ani[0][q]; xch[base + 28 + q] = ani[1][q];
        }
    }
    __syncthreads();

    if (w < 2) {
        int base = (w * 64 + lane) * 32;
        #pragma unroll
        for (int q = 0; q < 4; ++q) {
            ar[0][q]  += xch[base + 0 + q];  ar[1][q]  += xch[base + 4 + q];
            az[0][q]  += xch[base + 8 + q];  az[1][q]  += xch[base + 12 + q];
            anh[0][q] += xch[base + 16 + q]; anh[1][q] += xch[base + 20 + q];
            ani[0][q] += xch[base + 24 + q]; ani[1][q] += xch[base + 28 + q];
        }
        // gates: lane holds cols u = w*16+lid for 8 batch rows (2 rg x 4 regs)
        const int u = w * 16 + lid;
        const int j = jg * 32 + u;
        const float bIr = wsBias[(jg * 2 + 0) * 96 + w * 48 + lid];
        const float bHr = wsBias[(jg * 2 + 1) * 96 + w * 48 + lid];
        const float bIz = wsBias[(jg * 2 + 0) * 96 + w * 48 + 16 + lid];
        const float bHz = wsBias[(jg * 2 + 1) * 96 + w * 48 + 16 + lid];
        const float bIn = wsBias[(jg * 2 + 0) * 96 + w * 48 + 32 + lid];
        const float bHn = wsBias[(jg * 2 + 1) * 96 + w * 48 + 32 + lid];
        size_t xb0 = ((size_t)jg * 12 + (u >> 3)) * 2048 + (u & 7);
        #pragma unroll
        for (int rg = 0; rg < 2; ++rg) {
            #pragma unroll
            for (int q = 0; q < 4; ++q) {
                int brow = b0 + rg * 16 + kg * 4 + q;
                float xr = ar[rg][q] + bIr + bHr;
                float xz = az[rg][q] + bIz + bHz;
                float rr = 1.f / (1.f + expf(-xr));
                float zg = 1.f / (1.f + expf(-xz));
                float nn = tanhf((ani[rg][q] + bIn) + rr * (anh[rg][q] + bHn));
                float hold = Hr[(size_t)brow * kH + j];
                float hv = (1.f - zg) * nn + zg * hold;
                Hw[(size_t)brow * kH + j] = hv;
                unsigned short q0 = f2bf(hv);
                float r1 = hv - bf2f(q0);
                unsigned short q1 = f2bf(r1);
                unsigned short q2 = f2bf(r1 - bf2f(q1));
                size_t xb = xb0 + (size_t)brow * 8;
                Xw[xb] = q0; Xw[xb + 4 * 2048] = q1; Xw[xb + 8 * 2048] = q2;
                if (t == kT - 1) out[kB + (size_t)brow * kH + j] = hv;
            }
        }
    } else if (t + 1 < kT) {
        // waves 2,3: assemble next step's emb planes (runs parallel to gates)
        int ce = jg >> 1, par = jg & 1;
        int ttt = (w - 2) * 64 + lane;      // 0..127
        int rrow = ttt >> 3, kg2 = (ttt >> 1) & 3, h4 = ttt & 1;
        int brow = b0 + par * 16 + rrow;
        int tok = x[(size_t)brow * kT + (t + 1)];
        tok = (tok >= 0 && tok < VOCAB) ? tok : 0;
        int ke = ce * 32 + kg2 * 8 + h4 * 4;
        float4 v = *(const float4*)&emb[(size_t)tok * kE + ke];
        float vv[4] = {v.x, v.y, v.z, v.w};
        size_t base = ((size_t)(32 + ce) * 12 + kg2) * 2048 + (size_t)brow * 8 + h4 * 4;
        #pragma unroll
        for (int e = 0; e < 4; ++e) {
            float xx = vv[e];
            unsigned short q0 = f2bf(xx);
            float r1 = xx - bf2f(q0);
            unsigned short q1 = f2bf(r1);
            unsigned short q2 = f2bf(r1 - bf2f(q1));
            Xw[base + e] = q0;
            Xw[base + 4 * 2048 + e] = q1;
            Xw[base + 8 * 2048 + e] = q2;
        }
    }
}

// ---------------- final taps for samples with seq_len == T -------------------
__global__ void __launch_bounds__(NT)
gru_final2(const float* __restrict__ hf, const int* __restrict__ seq_len,
           const float* __restrict__ Wlin, const float* __restrict__ blin,
           float* __restrict__ out)
{
    __shared__ float red[NT];
    const int b = blockIdx.x, tid = threadIdx.x;
    if (seq_len[b] == kT) {
        const float* hr = hf + (size_t)b * kH;
        float4 v = *(const float4*)&hr[tid * 4];
        float4 wv = *(const float4*)&Wlin[tid * 4];
        red[tid] = v.x * wv.x + v.y * wv.y + v.z * wv.z + v.w * wv.w;
        __syncthreads();
        for (int s = NT / 2; s > 0; s >>= 1) {
            if (tid < s) red[tid] += red[tid + s];
            __syncthreads();
        }
        if (tid == 0) out[b] = 1.f / (1.f + expf(-(red[0] + blin[0])));
    }
}

// ======================= fallback path (round-3, proven) =====================
namespace fb {
constexpr int BB = 16, NC = 96, CK = 64;
constexpr int F4H = BB * (CK / 4);
constexpr int NPF = (BB + NC) * (CK / 4) / NT;
}

__global__ void __launch_bounds__(NT, 2)
gru_step_fb(const int* __restrict__ x, const int* __restrict__ seq_len,
            const float* __restrict__ emb, const float* __restrict__ Wih,
            const float* __restrict__ Whh, const float* __restrict__ bih,
            const float* __restrict__ bhh, const float* __restrict__ Wlin,
            const float* __restrict__ blin, const float* __restrict__ hc,
            float* __restrict__ hn, float* __restrict__ out, int t)
{
    using namespace fb;
    __shared__ float h_s[BB][CK + 4];
    __shared__ float w_s[NC][CK + 4];
    __shared__ float gI[NC][BB + 1];
    __shared__ float gH[NC][BB + 1];
    __shared__ float red[NT];
    __shared__ int sx[BB];
    __shared__ int ssl[BB];

    const int tid = threadIdx.x;
    const int bg = blockIdx.x >> 5, jg = blockIdx.x & 31;
    const int b0 = bg * BB, j0 = jg * 32;
    const int tb = (tid & 7) * 2, tc = (tid >> 3) * 3;
    const int gj = tid & 31, gb = (tid >> 5) * 2;

    if (tid < BB) {
        ssl[tid] = seq_len[b0 + tid];
        int v = x[(size_t)(b0 + tid) * kT + t];
        sx[tid] = (v >= 0 && v < VOCAB) ? v : 0;
    }
    __syncthreads();

    if (jg == 0 && t > 0) {
        for (int b = 0; b < BB; ++b) {
            if (ssl[b] == t) {
                const float* hr = hc + (size_t)(b0 + b) * kH;
                float p = 0.f;
                for (int k = tid; k < kH; k += NT) p += hr[k] * Wlin[k];
                red[tid] = p;
                __syncthreads();
                for (int s = NT / 2; s > 0; s >>= 1) {
                    if (tid < s) red[tid] += red[tid + s];
                    __syncthreads();
                }
                if (tid == 0) out[b0 + b] = 1.f / (1.f + expf(-(red[0] + blin[0])));
                __syncthreads();
            }
        }
    }

    float bI[3], bH[3];
    #pragma unroll
    for (int j = 0; j < 3; ++j) {
        int c = tc + j;
        int wrow = (c >> 5) * kH + j0 + (c & 31);
        bI[j] = bih[wrow]; bH[j] = bhh[wrow];
    }

    float4 pf[NPF];
    auto stage_commit = [&]() {
        #pragma unroll
        for (int l = 0; l < NPF; ++l) {
            int idx = l * NT + tid;
            if (idx < F4H) { int r = idx >> 4, q = idx & 15; *(float4*)&h_s[r][q * 4] = pf[l]; }
            else { int m = idx - F4H; int r = m >> 4, q = m & 15; *(float4*)&w_s[r][q * 4] = pf[l]; }
        }
    };
    auto issue_ih = [&](int k0) {
        #pragma unroll
        for (int l = 0; l < NPF; ++l) {
            int idx = l * NT + tid;
            if (idx < F4H) { int r = idx >> 4, q = idx & 15;
                pf[l] = *(const float4*)&emb[(size_t)sx[r] * kE + k0 + q * 4]; }
            else { int m = idx - F4H; int r = m >> 4, q = m & 15;
                int wrow = (r >> 5) * kH + j0 + (r & 31);
                pf[l] = *(const float4*)&Wih[(size_t)wrow * kE + k0 + q * 4]; }
        }
    };
    auto issue_hh = [&](int k0) {
        #pragma unroll
        for (int l = 0; l < NPF; ++l) {
            int idx = l * NT + tid;
            if (idx < F4H) { int r = idx >> 4, q = idx & 15;
                pf[l] = *(const float4*)&hc[(size_t)(b0 + r) * kH + k0 + q * 4]; }
            else { int m = idx - F4H; int r = m >> 4, q = m & 15;
                int wrow = (r >> 5) * kH + j0 + (r & 31);
                pf[l] = *(const float4*)&Whh[(size_t)wrow * kH + k0 + q * 4]; }
        }
    };
    auto gemm_chunk = [&](float (*acc)[3]) {
        #pragma unroll 2
        for (int kk = 0; kk < CK; kk += 4) {
            float4 hv[2], wv[3];
            #pragma unroll
            for (int i = 0; i < 2; ++i) hv[i] = *(const float4*)&h_s[tb + i][kk];
            #pragma unroll
            for (int j = 0; j < 3; ++j) wv[j] = *(const float4*)&w_s[tc + j][kk];
            #pragma unroll
            for (int i = 0; i < 2; ++i)
                #pragma unroll
                for (int j = 0; j < 3; ++j) {
                    acc[i][j] = fmaf(hv[i].x, wv[j].x, acc[i][j]);
                    acc[i][j] = fmaf(hv[i].y, wv[j].y, acc[i][j]);
                    acc[i][j] = fmaf(hv[i].z, wv[j].z, acc[i][j]);
                    acc[i][j] = fmaf(hv[i].w, wv[j].w, acc[i][j]);
                }
        }
    };

    float ai[2][3], ah[2][3];
    #pragma unroll
    for (int i = 0; i < 2; ++i)
        #pragma unroll
        for (int j = 0; j < 3; ++j) { ai[i][j] = 0.f; ah[i][j] = 0.f; }

    issue_ih(0);
    for (int k0 = 0; k0 < kE; k0 += CK) {
        __syncthreads();
        stage_commit();
        if (k0 + CK < kE) issue_ih(k0 + CK);
        __syncthreads();
        gemm_chunk(ai);
    }
    issue_hh(0);
    for (int k0 = 0; k0 < kH; k0 += CK) {
        __syncthreads();
        stage_commit();
        if (k0 + CK < kH) issue_hh(k0 + CK);
        __syncthreads();
        gemm_chunk(ah);
    }

    __syncthreads();
    #pragma unroll
    for (int j = 0; j < 3; ++j) {
        int c = tc + j;
        #pragma unroll
        for (int i = 0; i < 2; ++i) {
            gI[c][tb + i] = ai[i][j] + bI[j];
            gH[c][tb + i] = ah[i][j] + bH[j];
        }
    }
    __syncthreads();

    #pragma unroll
    for (int i = 0; i < 2; ++i) {
        int b = gb + i;
        float xr = gI[gj][b] + gH[gj][b];
        float xz = gI[32 + gj][b] + gH[32 + gj][b];
        float rr = 1.f / (1.f + expf(-xr));
        float zg = 1.f / (1.f + expf(-xz));
        float nn = tanhf(gI[64 + gj][b] + rr * gH[64 + gj][b]);
        size_t off = (size_t)(b0 + b) * kH + j0 + gj;
        float hold = hc[off];
        hn[off] = (1.f - zg) * nn + zg * hold;
    }
}

__global__ void __launch_bounds__(NT)
gru_final_fb(const float* __restrict__ hf, const int* __restrict__ seq_len,
             const float* __restrict__ Wlin, const float* __restrict__ blin,
             float* __restrict__ out)
{
    __shared__ float red[NT];
    const int b = blockIdx.x, tid = threadIdx.x;
    const float* hr = hf + (size_t)b * kH;
    float4 v = *(const float4*)&hr[tid * 4];
    *(float4*)&out[kB + (size_t)b * kH + tid * 4] = v;
    if (seq_len[b] == kT) {
        float4 wv = *(const float4*)&Wlin[tid * 4];
        red[tid] = v.x * wv.x + v.y * wv.y + v.z * wv.z + v.w * wv.w;
        __syncthreads();
        for (int s = NT / 2; s > 0; s >>= 1) {
            if (tid < s) red[tid] += red[tid + s];
            __syncthreads();
        }
        if (tid == 0) out[b] = 1.f / (1.f + expf(-(red[0] + blin[0])));
    }
}

// ============================================================================
extern "C" void kernel_launch(void* const* d_in, const int* in_sizes, int n_in,
                              void* d_out, int out_size, void* d_ws, size_t ws_size,
                              hipStream_t stream) {
    (void)in_sizes; (void)n_in; (void)out_size;
    const int*   x    = (const int*)  d_in[0];
    const float* h0   = (const float*)d_in[1];
    const int*   sl   = (const int*)  d_in[2];
    const float* emb  = (const float*)d_in[3];
    const float* Wih  = (const float*)d_in[4];
    const float* Whh  = (const float*)d_in[5];
    const float* bih  = (const float*)d_in[6];
    const float* bhh  = (const float*)d_in[7];
    const float* Wlin = (const float*)d_in[8];
    const float* blin = (const float*)d_in[9];
    float* out = (float*)d_out;

    if (ws_size >= WS_NEED) {
        unsigned short* wsW = (unsigned short*)((char*)d_ws + OFF_W);
        unsigned short* wsX = (unsigned short*)((char*)d_ws + OFF_X);
        float* wsH  = (float*)((char*)d_ws + OFF_H);
        float* wsBias = (float*)((char*)d_ws + OFF_BIAS);

        prep_w<<<32 * CH, 256, 0, stream>>>(Wih, Whh, bih, bhh, wsW, wsBias);
        prep_x0<<<CH, 256, 0, stream>>>(x, h0, emb, wsX, wsH);
        for (int t = 0; t < kT; ++t)
            gru_step_mfma<<<256, NT, 0, stream>>>(x, sl, emb, Wlin, blin,
                                                  wsW, wsBias, wsX, wsH, out, t);
        // h_512 lives in wsH buffer 0 (t=511 wrote buf (511&1)^1 = 0)
        gru_final2<<<kB, NT, 0, stream>>>(wsH, sl, Wlin, blin, out);
    } else {
        float* buf0 = (float*)d_ws;
        float* buf1 = (float*)d_ws + (size_t)kB * kH;
        for (int t = 0; t < kT; ++t) {
            const float* hc = (t == 0) ? h0 : ((t & 1) ? buf1 : buf0);
            float* hn = ((t + 1) & 1) ? buf1 : buf0;
            gru_step_fb<<<512, NT, 0, stream>>>(x, sl, emb, Wih, Whh, bih, bhh,
                                                Wlin, blin, hc, hn, out, t);
        }
        gru_final_fb<<<kB, NT, 0, stream>>>(buf0, sl, Wlin, blin, out);
    }
}

// Round 7
// 47133.884 us; speedup vs baseline: 1.2988x; 1.2988x over previous
//
#include <hip/hip_runtime.h>
#include <hip/hip_bf16.h>

typedef __attribute__((ext_vector_type(8))) short short8;
typedef __attribute__((ext_vector_type(4))) float f32x4;

namespace {
constexpr int kB = 256, kT = 512, kE = 512, kH = 1024;
constexpr int CH = 48;     // K chunks of 32 (0-31: h/Whh region, 32-47: emb/Wih region)
constexpr int NT = 256;
constexpr int VOCAB = 32000;

// ws layout (bytes). W pack: [jg 32][chunk 48][pl*4+kg 12][col 96][8] bf16
// X pack:  [buf 2][chunk 48][pl*4+kg 12][row 256][8] bf16
constexpr size_t W_ELEMS = (size_t)32 * CH * 12 * 96 * 8;
constexpr size_t X_ELEMS_BUF = (size_t)CH * 12 * 256 * 8;
constexpr size_t OFF_W = 0;
constexpr size_t OFF_X = W_ELEMS * 2;                       // 28,311,552
constexpr size_t OFF_H = OFF_X + X_ELEMS_BUF * 2 * 2;       // 33,030,144
constexpr size_t OFF_BIAS = OFF_H + (size_t)2 * kB * kH * 4; // 35,127,296
constexpr size_t WS_NEED = OFF_BIAS + (size_t)32 * 2 * 96 * 4;
}

__device__ __forceinline__ unsigned short f2bf(float f) {
    __hip_bfloat16 h = __float2bfloat16(f);
    return *reinterpret_cast<unsigned short*>(&h);
}
__device__ __forceinline__ float bf2f(unsigned short u) {
    __hip_bfloat16 h = *reinterpret_cast<__hip_bfloat16*>(&u);
    return __bfloat162float(h);
}

#define MFMA16(A_, B_, C_) __builtin_amdgcn_mfma_f32_16x16x32_bf16((A_), (B_), (C_), 0, 0, 0)

// ---------------- prep: split+reorder weights into MFMA-ready 3-plane pack ----
__global__ void __launch_bounds__(256)
prep_w(const float* __restrict__ Wih, const float* __restrict__ Whh,
       const float* __restrict__ bih, const float* __restrict__ bhh,
       unsigned short* __restrict__ wsW, float* __restrict__ wsBias)
{
    const int blk = blockIdx.x;          // jg*48 + c
    const int jg = blk / CH, c = blk % CH;
    const int tid = threadIdx.x;

    for (int u0 = tid; u0 < 384; u0 += 256) {     // (col, kg) units
        int col = u0 >> 2, kg = u0 & 3;
        int type = (col % 48) >> 4;
        int uu = (col / 48) * 16 + (col & 15);
        int grow = type * kH + jg * 32 + uu;
        float v[8];
        if (c < 32) {
            int kb = c * 32 + kg * 8;
            const float4* p = (const float4*)&Whh[(size_t)grow * kH + kb];
            float4 x0 = p[0], x1 = p[1];
            v[0]=x0.x; v[1]=x0.y; v[2]=x0.z; v[3]=x0.w;
            v[4]=x1.x; v[5]=x1.y; v[6]=x1.z; v[7]=x1.w;
        } else {
            int kb = (c - 32) * 32 + kg * 8;
            const float4* p = (const float4*)&Wih[(size_t)grow * kE + kb];
            float4 x0 = p[0], x1 = p[1];
            v[0]=x0.x; v[1]=x0.y; v[2]=x0.z; v[3]=x0.w;
            v[4]=x1.x; v[5]=x1.y; v[6]=x1.z; v[7]=x1.w;
        }
        size_t base = ((size_t)blk * 12 + kg) * 768 + (size_t)col * 8;  // pl=0 slot
        #pragma unroll
        for (int e = 0; e < 8; ++e) {
            float xx = v[e];
            unsigned short q0 = f2bf(xx);
            float r1 = xx - bf2f(q0);
            unsigned short q1 = f2bf(r1);
            unsigned short q2 = f2bf(r1 - bf2f(q1));
            wsW[base + e]            = q0;
            wsW[base + 4 * 768 + e]  = q1;   // pl stride = 4 slots of 768
            wsW[base + 8 * 768 + e]  = q2;
        }
    }
    if (c == 0 && tid < 96) {
        int col = tid;
        int type = (col % 48) >> 4;
        int uu = (col / 48) * 16 + (col & 15);
        int grow = type * kH + jg * 32 + uu;
        wsBias[(jg * 2 + 0) * 96 + col] = bih[grow];
        wsBias[(jg * 2 + 1) * 96 + col] = bhh[grow];
    }
}

// ---------------- prep: build X buffer 0 (h0 planes + emb(x[:,0]) planes) -----
__global__ void __launch_bounds__(256)
prep_x0(const int* __restrict__ x, const float* __restrict__ h0,
        const float* __restrict__ emb, unsigned short* __restrict__ wsX,
        float* __restrict__ wsH)
{
    const int c = blockIdx.x;           // 0..47
    const int tid = threadIdx.x;
    #pragma unroll 2
    for (int l = 0; l < 12; ++l) {
        int unit = l * 256 + tid;       // 0..3071
        int plkg = unit >> 8, b = unit & 255;
        int pl = plkg >> 2, kg = plkg & 3;
        float v[8];
        if (c < 32) {
            int j = c * 32 + kg * 8;
            const float4* p = (const float4*)&h0[(size_t)b * kH + j];
            float4 x0 = p[0], x1 = p[1];
            v[0]=x0.x; v[1]=x0.y; v[2]=x0.z; v[3]=x0.w;
            v[4]=x1.x; v[5]=x1.y; v[6]=x1.z; v[7]=x1.w;
            if (pl == 0) {
                #pragma unroll
                for (int e = 0; e < 8; ++e) wsH[(size_t)b * kH + j + e] = v[e];
            }
        } else {
            int tok = x[(size_t)b * kT];
            tok = (tok >= 0 && tok < VOCAB) ? tok : 0;
            int ke = (c - 32) * 32 + kg * 8;
            const float4* p = (const float4*)&emb[(size_t)tok * kE + ke];
            float4 x0 = p[0], x1 = p[1];
            v[0]=x0.x; v[1]=x0.y; v[2]=x0.z; v[3]=x0.w;
            v[4]=x1.x; v[5]=x1.y; v[6]=x1.z; v[7]=x1.w;
        }
        size_t base = ((size_t)c * 12 + plkg) * 2048 + (size_t)b * 8;
        #pragma unroll
        for (int e = 0; e < 8; ++e) {
            float xx = v[e];
            unsigned short q0 = f2bf(xx);
            float r1 = xx - bf2f(q0);
            unsigned short q1 = f2bf(r1);
            unsigned short q2 = f2bf(r1 - bf2f(q1));
            unsigned short q = (pl == 0) ? q0 : ((pl == 1) ? q1 : q2);
            wsX[base + e] = q;
        }
    }
}

// ---------------- per-step MFMA GRU kernel -----------------------------------
// Grid 256 = 8 bg x 32 jg (jg%8 = XCD). Main-loop sync discipline is T3/T4:
// counted `s_waitcnt vmcnt(12)` + raw s_barrier — NEVER vmcnt(0) in steady
// state. Round-5-measured: __syncthreads() drained the 2-ahead prefetch
// every iteration (compiler emits vmcnt(0) before s_barrier), exposing full
// L3/HBM latency 24x per step -> 61 ms. Two pf buffers (pair parity) keep
// loads in flight across barriers.
// NOTE: s_barrier is emitted via asm volatile with "memory" clobber — the
// raw __builtin_amdgcn_s_barrier() is NOT a compiler memory fence, and
// compute()'s LDS reads must not hoist above the barrier (race with other
// waves' commit stores).
__global__ void __launch_bounds__(NT, 1)
gru_step_mfma(const int* __restrict__ x, const int* __restrict__ seq_len,
              const float* __restrict__ emb, const float* __restrict__ Wlin,
              const float* __restrict__ blin,
              const unsigned short* __restrict__ wsW,
              const float* __restrict__ wsBias,
              unsigned short* __restrict__ wsX, float* __restrict__ wsH,
              float* __restrict__ out, int t)
{
    __shared__ __align__(16) short lds[49152];  // 96 KB: A 4 slots x 384 int4, B 4 x 1152 int4
    __shared__ float red[NT];
    __shared__ int ssl[32];

    const int tid = threadIdx.x;
    const int bg = blockIdx.x >> 5, jg = blockIdx.x & 31;
    const int b0 = bg * 32;
    const int w = tid >> 6, lane = tid & 63, lid = lane & 15, kg = lane >> 4;

    const int bufR = t & 1, bufW = bufR ^ 1;
    const unsigned short* Xr = wsX + (size_t)bufR * X_ELEMS_BUF;
    unsigned short* Xw = wsX + (size_t)bufW * X_ELEMS_BUF;
    const float* Hr = wsH + (size_t)bufR * kB * kH;
    float* Hw = wsH + (size_t)bufW * kB * kH;

    if (tid < 32) ssl[tid] = seq_len[b0 + tid];
    __syncthreads();

    // output tap: sample b finished at step t-1 iff ssl==t (Hr holds h_t)
    if (jg == 0 && t > 0) {
        for (int b = 0; b < 32; ++b) {
            if (ssl[b] == t) {
                const float* hr = Hr + (size_t)(b0 + b) * kH;
                float p = 0.f;
                for (int k = tid; k < kH; k += NT) p += hr[k] * Wlin[k];
                red[tid] = p;
                __syncthreads();
                for (int s = NT / 2; s > 0; s >>= 1) {
                    if (tid < s) red[tid] += red[tid + s];
                    __syncthreads();
                }
                if (tid == 0) out[b0 + b] = 1.f / (1.f + expf(-(red[0] + blin[0])));
                __syncthreads();
            }
        }
    }

    const int4* gW = (const int4*)wsW;
    const int4* gX = (const int4*)Xr;
    int4* lA = (int4*)lds;                 // 4 slots x 384 units
    int4* lB = (int4*)(lds + 12288);       // 4 slots x 1152 units
    int4 pfA[12], pfB[12];                 // pair parity: even pairs->A, odd->B

    // Single vmem instr per l (ternary ADDRESS select, branch-free): makes the
    // per-wave outstanding-load count exactly 12 per issue() -> vmcnt(12) is
    // a precise "previous pair arrived" wait.
    auto issue = [&](int pair, int4 (&pf)[12]) {
        #pragma unroll
        for (int l = 0; l < 12; ++l) {
            int u = l * 256 + tid;
            int hi = (u >= 1536);
            int cc = 2 * pair + hi;
            int v = u - (hi ? 1536 : 0);
            int wv = v - 1152;             // valid only when v>=1152
            const int4* pw = &gW[(size_t)(jg * CH + cc) * 1152 + v];
            const int4* px = &gX[(size_t)(cc * 12 + (wv >> 5)) * 256 + (b0 + (wv & 31))];
            pf[l] = *((v < 1152) ? pw : px);
        }
    };
    auto commit = [&](int pair, int4 (&pf)[12]) {
        #pragma unroll
        for (int l = 0; l < 12; ++l) {
            int u = l * 256 + tid;
            int hi = (u >= 1536);
            int cc = 2 * pair + hi;
            int v = u - (hi ? 1536 : 0);
            int4* pl_ = (v < 1152) ? &lB[(cc & 3) * 1152 + v]
                                   : &lA[(cc & 3) * 384 + (v - 1152)];
            *pl_ = pf[l];
        }
    };

    f32x4 zz4 = {0.f, 0.f, 0.f, 0.f};
    f32x4 ar[2] = {zz4, zz4}, az[2] = {zz4, zz4};
    f32x4 anh[2] = {zz4, zz4}, ani[2] = {zz4, zz4};
    const int pr = w >> 1, half = w & 1;

    auto compute = [&](int c) {
        const short* A = lds + (c & 3) * 3072;
        const short* B = lds + 12288 + (c & 3) * 9216;
        short8 fa[3][2], fb[3][3];
        #pragma unroll
        for (int pl = 0; pl < 3; ++pl) {
            #pragma unroll
            for (int rg = 0; rg < 2; ++rg)
                fa[pl][rg] = *(const short8*)&A[(pl * 4 + kg) * 256 + (rg * 16 + lid) * 8];
            #pragma unroll
            for (int cg = 0; cg < 3; ++cg)
                fb[pl][cg] = *(const short8*)&B[(pl * 4 + kg) * 768 + (half * 48 + cg * 16 + lid) * 8];
        }
        const int TA[6] = {0, 0, 1, 0, 2, 1};
        const int TB[6] = {0, 1, 0, 2, 0, 1};
        #pragma unroll
        for (int s = 0; s < 6; ++s) {
            #pragma unroll
            for (int rg = 0; rg < 2; ++rg) {
                ar[rg] = MFMA16(fa[TA[s]][rg], fb[TB[s]][0], ar[rg]);
                az[rg] = MFMA16(fa[TA[s]][rg], fb[TB[s]][1], az[rg]);
            }
        }
        if (c < 32) {
            #pragma unroll
            for (int s = 0; s < 6; ++s)
                #pragma unroll
                for (int rg = 0; rg < 2; ++rg)
                    anh[rg] = MFMA16(fa[TA[s]][rg], fb[TB[s]][2], anh[rg]);
        } else {
            #pragma unroll
            for (int s = 0; s < 6; ++s)
                #pragma unroll
                for (int rg = 0; rg < 2; ++rg)
                    ani[rg] = MFMA16(fa[TA[s]][rg], fb[TB[s]][2], ani[rg]);
        }
    };

    #define VM12 asm volatile("s_waitcnt vmcnt(12)" ::: "memory")
    #define VM0  asm volatile("s_waitcnt vmcnt(0)"  ::: "memory")
    #define LG0  asm volatile("s_waitcnt lgkmcnt(0)" ::: "memory")
    #define BAR  asm volatile("s_barrier" ::: "memory")

    // prologue: pairs 0,1 in flight; commit pair0; one barrier
    issue(0, pfA);
    issue(1, pfB);
    VM12;                 // pair0 arrived (pair1 may remain in flight)
    commit(0, pfA);
    LG0; BAR;

    // main loop: 12 x 2 iterations, buffer parity static per half (rule #20)
    for (int ii = 0; ii < 12; ++ii) {
        {   // even step: i0 = 2*ii  (issue->pfA, commit->pfB)
            const int i0 = 2 * ii;
            if (i0 + 2 < 24) issue(i0 + 2, pfA);
            compute(2 * i0 + pr);
            if (i0 + 3 < 24) { VM12; } else { VM0; }
            commit(i0 + 1, pfB);       // WAR-safe: adjacent pairs use disjoint slots
            LG0; BAR;
        }
        {   // odd step: i1 = 2*ii+1  (issue->pfB, commit->pfA)
            const int i1 = 2 * ii + 1;
            if (i1 + 2 < 24) issue(i1 + 2, pfB);
            compute(2 * i1 + pr);
            if (i1 + 1 < 24) {
                if (i1 + 3 < 24) { VM12; } else { VM0; }
                commit(i1 + 1, pfA);
                LG0; BAR;
            }
        }
    }
    __syncthreads();   // full drain before LDS reuse as fp32 exchange buffer

    // cross-pair reduction: waves 2,3 export partial accs via LDS
    float* xch = (float*)lds;
    if (w >= 2) {
        int base = ((w - 2) * 64 + lane) * 32;
        #pragma unroll
        for (int q = 0; q < 4; ++q) {
            xch[base + 0 + q]  = ar[0][q];  xch[base + 4 + q]  = ar[1][q];
            xch[base + 8 + q]  = az[0][q];  xch[base + 12 + q] = az[1][q];
            xch[base + 16 + q] = anh[0][q]; xch[base + 20 + q] = anh[1][q];
            xch[base + 24 + q] = ani[0][q]; xch[base + 28 + q] = ani[1][q];
        }
    }
    __syncthreads();

    if (w < 2) {
        int base = (w * 64 + lane) * 32;
        #pragma unroll
        for (int q = 0; q < 4; ++q) {
            ar[0][q]  += xch[base + 0 + q];  ar[1][q]  += xch[base + 4 + q];
            az[0][q]  += xch[base + 8 + q];  az[1][q]  += xch[base + 12 + q];
            anh[0][q] += xch[base + 16 + q]; anh[1][q] += xch[base + 20 + q];
            ani[0][q] += xch[base + 24 + q]; ani[1][q] += xch[base + 28 + q];
        }
        // gates: lane holds cols u = w*16+lid for 8 batch rows (2 rg x 4 regs)
        const int u = w * 16 + lid;
        const int j = jg * 32 + u;
        const float bIr = wsBias[(jg * 2 + 0) * 96 + w * 48 + lid];
        const float bHr = wsBias[(jg * 2 + 1) * 96 + w * 48 + lid];
        const float bIz = wsBias[(jg * 2 + 0) * 96 + w * 48 + 16 + lid];
        const float bHz = wsBias[(jg * 2 + 1) * 96 + w * 48 + 16 + lid];
        const float bIn = wsBias[(jg * 2 + 0) * 96 + w * 48 + 32 + lid];
        const float bHn = wsBias[(jg * 2 + 1) * 96 + w * 48 + 32 + lid];
        size_t xb0 = ((size_t)jg * 12 + (u >> 3)) * 2048 + (u & 7);
        #pragma unroll
        for (int rg = 0; rg < 2; ++rg) {
            #pragma unroll
            for (int q = 0; q < 4; ++q) {
                int brow = b0 + rg * 16 + kg * 4 + q;
                float xr = ar[rg][q] + bIr + bHr;
                float xz = az[rg][q] + bIz + bHz;
                float rr = 1.f / (1.f + expf(-xr));
                float zg = 1.f / (1.f + expf(-xz));
                float nn = tanhf((ani[rg][q] + bIn) + rr * (anh[rg][q] + bHn));
                float hold = Hr[(size_t)brow * kH + j];
                float hv = (1.f - zg) * nn + zg * hold;
                Hw[(size_t)brow * kH + j] = hv;
                unsigned short q0 = f2bf(hv);
                float r1 = hv - bf2f(q0);
                unsigned short q1 = f2bf(r1);
                unsigned short q2 = f2bf(r1 - bf2f(q1));
                size_t xb = xb0 + (size_t)brow * 8;
                Xw[xb] = q0; Xw[xb + 4 * 2048] = q1; Xw[xb + 8 * 2048] = q2;
                if (t == kT - 1) out[kB + (size_t)brow * kH + j] = hv;
            }
        }
    } else if (t + 1 < kT) {
        // waves 2,3: assemble next step's emb planes (runs parallel to gates)
        int ce = jg >> 1, par = jg & 1;
        int ttt = (w - 2) * 64 + lane;      // 0..127
        int rrow = ttt >> 3, kg2 = (ttt >> 1) & 3, h4 = ttt & 1;
        int brow = b0 + par * 16 + rrow;
        int tok = x[(size_t)brow * kT + (t + 1)];
        tok = (tok >= 0 && tok < VOCAB) ? tok : 0;
        int ke = ce * 32 + kg2 * 8 + h4 * 4;
        float4 v = *(const float4*)&emb[(size_t)tok * kE + ke];
        float vv[4] = {v.x, v.y, v.z, v.w};
        size_t base = ((size_t)(32 + ce) * 12 + kg2) * 2048 + (size_t)brow * 8 + h4 * 4;
        #pragma unroll
        for (int e = 0; e < 4; ++e) {
            float xx = vv[e];
            unsigned short q0 = f2bf(xx);
            float r1 = xx - bf2f(q0);
            unsigned short q1 = f2bf(r1);
            unsigned short q2 = f2bf(r1 - bf2f(q1));
            Xw[base + e] = q0;
            Xw[base + 4 * 2048 + e] = q1;
            Xw[base + 8 * 2048 + e] = q2;
        }
    }
    #undef VM12
    #undef VM0
    #undef LG0
    #undef BAR
}

// ---------------- final taps for samples with seq_len == T -------------------
__global__ void __launch_bounds__(NT)
gru_final2(const float* __restrict__ hf, const int* __restrict__ seq_len,
           const float* __restrict__ Wlin, const float* __restrict__ blin,
           float* __restrict__ out)
{
    __shared__ float red[NT];
    const int b = blockIdx.x, tid = threadIdx.x;
    if (seq_len[b] == kT) {
        const float* hr = hf + (size_t)b * kH;
        float4 v = *(const float4*)&hr[tid * 4];
        float4 wv = *(const float4*)&Wlin[tid * 4];
        red[tid] = v.x * wv.x + v.y * wv.y + v.z * wv.z + v.w * wv.w;
        __syncthreads();
        for (int s = NT / 2; s > 0; s >>= 1) {
            if (tid < s) red[tid] += red[tid + s];
            __syncthreads();
        }
        if (tid == 0) out[b] = 1.f / (1.f + expf(-(red[0] + blin[0])));
    }
}

// ======================= fallback path (round-3, proven) =====================
namespace fb {
constexpr int BB = 16, NC = 96, CK = 64;
constexpr int F4H = BB * (CK / 4);
constexpr int NPF = (BB + NC) * (CK / 4) / NT;
}

__global__ void __launch_bounds__(NT, 2)
gru_step_fb(const int* __restrict__ x, const int* __restrict__ seq_len,
            const float* __restrict__ emb, const float* __restrict__ Wih,
            const float* __restrict__ Whh, const float* __restrict__ bih,
            const float* __restrict__ bhh, const float* __restrict__ Wlin,
            const float* __restrict__ blin, const float* __restrict__ hc,
            float* __restrict__ hn, float* __restrict__ out, int t)
{
    using namespace fb;
    __shared__ float h_s[BB][CK + 4];
    __shared__ float w_s[NC][CK + 4];
    __shared__ float gI[NC][BB + 1];
    __shared__ float gH[NC][BB + 1];
    __shared__ float red[NT];
    __shared__ int sx[BB];
    __shared__ int ssl[BB];

    const int tid = threadIdx.x;
    const int bg = blockIdx.x >> 5, jg = blockIdx.x & 31;
    const int b0 = bg * BB, j0 = jg * 32;
    const int tb = (tid & 7) * 2, tc = (tid >> 3) * 3;
    const int gj = tid & 31, gb = (tid >> 5) * 2;

    if (tid < BB) {
        ssl[tid] = seq_len[b0 + tid];
        int v = x[(size_t)(b0 + tid) * kT + t];
        sx[tid] = (v >= 0 && v < VOCAB) ? v : 0;
    }
    __syncthreads();

    if (jg == 0 && t > 0) {
        for (int b = 0; b < BB; ++b) {
            if (ssl[b] == t) {
                const float* hr = hc + (size_t)(b0 + b) * kH;
                float p = 0.f;
                for (int k = tid; k < kH; k += NT) p += hr[k] * Wlin[k];
                red[tid] = p;
                __syncthreads();
                for (int s = NT / 2; s > 0; s >>= 1) {
                    if (tid < s) red[tid] += red[tid + s];
                    __syncthreads();
                }
                if (tid == 0) out[b0 + b] = 1.f / (1.f + expf(-(red[0] + blin[0])));
                __syncthreads();
            }
        }
    }

    float bI[3], bH[3];
    #pragma unroll
    for (int j = 0; j < 3; ++j) {
        int c = tc + j;
        int wrow = (c >> 5) * kH + j0 + (c & 31);
        bI[j] = bih[wrow]; bH[j] = bhh[wrow];
    }

    float4 pf[NPF];
    auto stage_commit = [&]() {
        #pragma unroll
        for (int l = 0; l < NPF; ++l) {
            int idx = l * NT + tid;
            if (idx < F4H) { int r = idx >> 4, q = idx & 15; *(float4*)&h_s[r][q * 4] = pf[l]; }
            else { int m = idx - F4H; int r = m >> 4, q = m & 15; *(float4*)&w_s[r][q * 4] = pf[l]; }
        }
    };
    auto issue_ih = [&](int k0) {
        #pragma unroll
        for (int l = 0; l < NPF; ++l) {
            int idx = l * NT + tid;
            if (idx < F4H) { int r = idx >> 4, q = idx & 15;
                pf[l] = *(const float4*)&emb[(size_t)sx[r] * kE + k0 + q * 4]; }
            else { int m = idx - F4H; int r = m >> 4, q = m & 15;
                int wrow = (r >> 5) * kH + j0 + (r & 31);
                pf[l] = *(const float4*)&Wih[(size_t)wrow * kE + k0 + q * 4]; }
        }
    };
    auto issue_hh = [&](int k0) {
        #pragma unroll
        for (int l = 0; l < NPF; ++l) {
            int idx = l * NT + tid;
            if (idx < F4H) { int r = idx >> 4, q = idx & 15;
                pf[l] = *(const float4*)&hc[(size_t)(b0 + r) * kH + k0 + q * 4]; }
            else { int m = idx - F4H; int r = m >> 4, q = m & 15;
                int wrow = (r >> 5) * kH + j0 + (r & 31);
                pf[l] = *(const float4*)&Whh[(size_t)wrow * kH + k0 + q * 4]; }
        }
    };
    auto gemm_chunk = [&](float (*acc)[3]) {
        #pragma unroll 2
        for (int kk = 0; kk < CK; kk += 4) {
            float4 hv[2], wv[3];
            #pragma unroll
            for (int i = 0; i < 2; ++i) hv[i] = *(const float4*)&h_s[tb + i][kk];
            #pragma unroll
            for (int j = 0; j < 3; ++j) wv[j] = *(const float4*)&w_s[tc + j][kk];
            #pragma unroll
            for (int i = 0; i < 2; ++i)
                #pragma unroll
                for (int j = 0; j < 3; ++j) {
                    acc[i][j] = fmaf(hv[i].x, wv[j].x, acc[i][j]);
                    acc[i][j] = fmaf(hv[i].y, wv[j].y, acc[i][j]);
                    acc[i][j] = fmaf(hv[i].z, wv[j].z, acc[i][j]);
                    acc[i][j] = fmaf(hv[i].w, wv[j].w, acc[i][j]);
                }
        }
    };

    float ai[2][3], ah[2][3];
    #pragma unroll
    for (int i = 0; i < 2; ++i)
        #pragma unroll
        for (int j = 0; j < 3; ++j) { ai[i][j] = 0.f; ah[i][j] = 0.f; }

    issue_ih(0);
    for (int k0 = 0; k0 < kE; k0 += CK) {
        __syncthreads();
        stage_commit();
        if (k0 + CK < kE) issue_ih(k0 + CK);
        __syncthreads();
        gemm_chunk(ai);
    }
    issue_hh(0);
    for (int k0 = 0; k0 < kH; k0 += CK) {
        __syncthreads();
        stage_commit();
        if (k0 + CK < kH) issue_hh(k0 + CK);
        __syncthreads();
        gemm_chunk(ah);
    }

    __syncthreads();
    #pragma unroll
    for (int j = 0; j < 3; ++j) {
        int c = tc + j;
        #pragma unroll
        for (int i = 0; i < 2; ++i) {
            gI[c][tb + i] = ai[i][j] + bI[j];
            gH[c][tb + i] = ah[i][j] + bH[j];
        }
    }
    __syncthreads();

    #pragma unroll
    for (int i = 0; i < 2; ++i) {
        int b = gb + i;
        float xr = gI[gj][b] + gH[gj][b];
        float xz = gI[32 + gj][b] + gH[32 + gj][b];
        float rr = 1.f / (1.f + expf(-xr));
        float zg = 1.f / (1.f + expf(-xz));
        float nn = tanhf(gI[64 + gj][b] + rr * gH[64 + gj][b]);
        size_t off = (size_t)(b0 + b) * kH + j0 + gj;
        float hold = hc[off];
        hn[off] = (1.f - zg) * nn + zg * hold;
    }
}

__global__ void __launch_bounds__(NT)
gru_final_fb(const float* __restrict__ hf, const int* __restrict__ seq_len,
             const float* __restrict__ Wlin, const float* __restrict__ blin,
             float* __restrict__ out)
{
    __shared__ float red[NT];
    const int b = blockIdx.x, tid = threadIdx.x;
    const float* hr = hf + (size_t)b * kH;
    float4 v = *(const float4*)&hr[tid * 4];
    *(float4*)&out[kB + (size_t)b * kH + tid * 4] = v;
    if (seq_len[b] == kT) {
        float4 wv = *(const float4*)&Wlin[tid * 4];
        red[tid] = v.x * wv.x + v.y * wv.y + v.z * wv.z + v.w * wv.w;
        __syncthreads();
        for (int s = NT / 2; s > 0; s >>= 1) {
            if (tid < s) red[tid] += red[tid + s];
            __syncthreads();
        }
        if (tid == 0) out[b] = 1.f / (1.f + expf(-(red[0] + blin[0])));
    }
}

// ============================================================================
extern "C" void kernel_launch(void* const* d_in, const int* in_sizes, int n_in,
                              void* d_out, int out_size, void* d_ws, size_t ws_size,
                              hipStream_t stream) {
    (void)in_sizes; (void)n_in; (void)out_size;
    const int*   x    = (const int*)  d_in[0];
    const float* h0   = (const float*)d_in[1];
    const int*   sl   = (const int*)  d_in[2];
    const float* emb  = (const float*)d_in[3];
    const float* Wih  = (const float*)d_in[4];
    const float* Whh  = (const float*)d_in[5];
    const float* bih  = (const float*)d_in[6];
    const float* bhh  = (const float*)d_in[7];
    const float* Wlin = (const float*)d_in[8];
    const float* blin = (const float*)d_in[9];
    float* out = (float*)d_out;

    if (ws_size >= WS_NEED) {
        unsigned short* wsW = (unsigned short*)((char*)d_ws + OFF_W);
        unsigned short* wsX = (unsigned short*)((char*)d_ws + OFF_X);
        float* wsH  = (float*)((char*)d_ws + OFF_H);
        float* wsBias = (float*)((char*)d_ws + OFF_BIAS);

        prep_w<<<32 * CH, 256, 0, stream>>>(Wih, Whh, bih, bhh, wsW, wsBias);
        prep_x0<<<CH, 256, 0, stream>>>(x, h0, emb, wsX, wsH);
        for (int t = 0; t < kT; ++t)
            gru_step_mfma<<<256, NT, 0, stream>>>(x, sl, emb, Wlin, blin,
                                                  wsW, wsBias, wsX, wsH, out, t);
        // h_512 lives in wsH buffer 0 (t=511 wrote buf (511&1)^1 = 0)
        gru_final2<<<kB, NT, 0, stream>>>(wsH, sl, Wlin, blin, out);
    } else {
        float* buf0 = (float*)d_ws;
        float* buf1 = (float*)d_ws + (size_t)kB * kH;
        for (int t = 0; t < kT; ++t) {
            const float* hc = (t == 0) ? h0 : ((t & 1) ? buf1 : buf0);
            float* hn = ((t + 1) & 1) ? buf1 : buf0;
            gru_step_fb<<<512, NT, 0, stream>>>(x, sl, emb, Wih, Whh, bih, bhh,
                                                Wlin, blin, hc, hn, out, t);
        }
        gru_final_fb<<<kB, NT, 0, stream>>>(buf0, sl, Wlin, blin, out);
    }
}